// Round 7
// baseline (294.791 us; speedup 1.0000x reference)
//
#include <hip/hip_runtime.h>
#include <math.h>

// ---------------------------------------------------------------------------
// ArithmeticNps: B=16384, CV=128, CR=64, NR=16, CM_RULE=128
//   setupA : zero padded rule counters; precompute read1[16][32],
//            read2[16][2][16], w1ope[3][32].
//   setupB : fold encoder w2 into rule_W1: W1h[r] (128x128), b1h[r].
//   stage1 : 8 threads per element (one wave = 8 elems). x in registers
//            (bitwise-identical fma order to the passing round-5 kernel),
//            w1/w2 via __shfl_xor tree reduction, h recomputed on the fly.
//            LDS ~5KB (padded read1/read2 tables only), 3 barriers.
//   stage2 : per (rule, 32 elems): GEMM1 K=128 (W1h) + GEMM2 + fused decoder.
// ---------------------------------------------------------------------------

#define OFF_READ1 0        // 512
#define OFF_READ2 512      // 512
#define OFF_W1OPE 1024     // 96 (pad to 128)
#define OFF_W1H   1152     // 16*128*128 = 262144
#define OFF_B1H   263296   // 16*128 = 2048
#define OFF_VARH  265344   // B*128

// ---------------------------------------------------------------------------
__global__ __launch_bounds__(256) void setupA(
    const float* __restrict__ rules_emb, const float* __restrict__ s1_k_w,
    const float* __restrict__ s1_k_b,   const float* __restrict__ s2_k_w,
    const float* __restrict__ s2_k_b,
    const float* __restrict__ enc_opr_w1, const float* __restrict__ enc_opr_b1,
    const float* __restrict__ enc_opr_w2, const float* __restrict__ enc_opr_b2,
    const float* __restrict__ s1_q_w, const float* __restrict__ s1_q_b,
    int* __restrict__ cnt, float* __restrict__ fws)
{
    const int t = threadIdx.x;
    if (t < 16) cnt[t * 32] = 0;   // padded counters: one per cache line

    __shared__ float ope_s[3 * 128];
    for (int idx = t; idx < 3 * 128; idx += 256) {
        int v = idx >> 7, c = idx & 127;
        float o = enc_opr_b2[c];
        for (int j = 0; j < 64; ++j) {
            float h = fmaxf(enc_opr_w1[v * 64 + j] + enc_opr_b1[j], 0.f);
            o = fmaf(h, enc_opr_w2[j * 128 + c], o);
        }
        ope_s[idx] = o;
    }
    __syncthreads();

    // w1ope[v][m]
    for (int idx = t; idx < 96; idx += 256) {
        int v = idx >> 5, m = idx & 31;
        float a = s1_q_b[m];
        for (int c = 0; c < 128; ++c)
            a = fmaf(ope_s[v * 128 + c], s1_q_w[c * 32 + m], a);
        fws[OFF_W1OPE + idx] = a;
    }
    // read1[n][m]
    for (int idx = t; idx < 512; idx += 256) {
        int n = idx >> 5;
        float a = s1_k_b[idx];
        for (int r = 0; r < 64; ++r)
            a = fmaf(rules_emb[n * 64 + r], s1_k_w[(n * 64 + r) * 32 + (idx & 31)], a);
        fws[OFF_READ1 + idx] = a;
    }
    // read2[r][n][m]
    for (int idx = t; idx < 512; idx += 256) {
        int r = idx >> 5, n = (idx >> 4) & 1, m = idx & 15;
        float a = s2_k_b[n * 16 + m];
        for (int j = 0; j < 64; ++j)
            a = fmaf(rules_emb[r * 64 + j], s2_k_w[(n * 64 + j) * 16 + m], a);
        fws[OFF_READ2 + idx] = a;
    }
}

// ---------------------------------------------------------------------------
// W1h[r][half*64+j][m] = sum_c w2[j][c] * rule_W1[r][half*128+c][m]
__global__ __launch_bounds__(256) void setupB(
    const float* __restrict__ enc_op_w2, const float* __restrict__ enc_op_b2,
    const float* __restrict__ rule_W1,   const float* __restrict__ rule_b1,
    float* __restrict__ fws)
{
    const int r = blockIdx.x, half = blockIdx.y;
    const int t = threadIdx.x;
    const int colg = t & 15, rowg = t >> 4;   // j = rowg*4..+4, m = colg*8..+8
    const float* W1src = &rule_W1[((size_t)r * 256 + half * 128) * 128];

    float acc[4][8];
    #pragma unroll
    for (int i = 0; i < 4; ++i)
        #pragma unroll
        for (int j = 0; j < 8; ++j) acc[i][j] = 0.f;

    #pragma unroll 2
    for (int c = 0; c < 128; ++c) {
        const float4 wa = *(const float4*)&W1src[c * 128 + colg * 8];
        const float4 wb = *(const float4*)&W1src[c * 128 + colg * 8 + 4];
        #pragma unroll
        for (int i = 0; i < 4; ++i) {
            float w = enc_op_w2[(rowg * 4 + i) * 128 + c];
            acc[i][0] = fmaf(w, wa.x, acc[i][0]); acc[i][1] = fmaf(w, wa.y, acc[i][1]);
            acc[i][2] = fmaf(w, wa.z, acc[i][2]); acc[i][3] = fmaf(w, wa.w, acc[i][3]);
            acc[i][4] = fmaf(w, wb.x, acc[i][4]); acc[i][5] = fmaf(w, wb.y, acc[i][5]);
            acc[i][6] = fmaf(w, wb.z, acc[i][6]); acc[i][7] = fmaf(w, wb.w, acc[i][7]);
        }
    }
    #pragma unroll
    for (int i = 0; i < 4; ++i)
        #pragma unroll
        for (int j = 0; j < 8; ++j)
            fws[OFF_W1H + r * 16384 + (half * 64 + rowg * 4 + i) * 128 + colg * 8 + j] = acc[i][j];

    // b1h[r][m] = b1[r][m] + sum_c b2[c]*(W1[c][m] + W1[128+c][m])
    if (half == 0 && t < 128) {
        const float* W1r = &rule_W1[(size_t)r * 256 * 128];
        float b = rule_b1[r * 128 + t];
        for (int c = 0; c < 128; ++c)
            b += enc_op_b2[c] * (W1r[c * 128 + t] + W1r[(128 + c) * 128 + t]);
        fws[OFF_B1H + r * 128 + t] = b;
    }
}

// ---------------------------------------------------------------------------
__global__ __launch_bounds__(256) void stage1(
    const float* __restrict__ op1, const float* __restrict__ op2,
    const int* __restrict__ opr,
    const float* __restrict__ enc_op_w1, const float* __restrict__ enc_op_b1,
    const float* __restrict__ enc_op_w2, const float* __restrict__ enc_op_b2,
    const float* __restrict__ s1_q_w,   const float* __restrict__ s1_q_b,
    const float* __restrict__ s2_q_w,   const float* __restrict__ s2_q_b,
    int* __restrict__ cnt, int* __restrict__ bucket,
    float* __restrict__ fws, int B)
{
    const int t   = threadIdx.x;
    const int blk = blockIdx.x;
    const int e   = t >> 3;        // element within block (0..31)
    const int sub = t & 7;         // 8 threads per element (same wave)
    const int elem = blk * 32 + e;

    __shared__ float r1s[16 * 33];   // read1 padded (bank-conflict-free col reads)
    __shared__ float r2s[16 * 34];   // read2 padded
    __shared__ float wops[3 * 33];   // w1ope padded
    __shared__ int lcnt[16], lpos[32], base[16];

    for (int i = t; i < 512; i += 256) r1s[(i >> 5) * 33 + (i & 31)] = fws[OFF_READ1 + i];
    for (int i = t; i < 512; i += 256) r2s[(i >> 5) * 34 + (i & 31)] = fws[OFF_READ2 + i];
    if (t < 96) wops[(t >> 5) * 33 + (t & 31)] = fws[OFF_W1OPE + t];
    if (t < 16) lcnt[t] = 0;
    __syncthreads();

    const float o1 = op1[elem];
    const float o2 = op2[elem];
    const int   op = opr[elem];

    const int n0 = sub * 2, n1 = sub * 2 + 1;
    float w2r0[16], w2r1[16];
    float bv0 = -INFINITY, bv1 = -INFINITY;   // running max over k for n0, n1

    #pragma unroll
    for (int k = 0; k < 2; ++k) {
        const float o = k ? o2 : o1;

        // x columns c = sub*16 .. +16 (bitwise-identical order to round 5:
        // init bias, j ascending, h = relu(fma(o, w0, beff)))
        float x[16];
        #pragma unroll
        for (int i = 0; i < 16; ++i) x[i] = enc_op_b2[sub * 16 + i];
        #pragma unroll 4
        for (int j = 0; j < 64; ++j) {
            float bj   = enc_op_b1[j];
            float beff = k ? (enc_op_w1[64 + j] + bj) : bj;
            float hj   = fmaxf(fmaf(o, enc_op_w1[j], beff), 0.f);
            const float* wr = &enc_op_w2[j * 128 + sub * 16];
            #pragma unroll
            for (int i = 0; i < 16; ++i) x[i] = fmaf(hj, wr[i], x[i]);
        }

        // partial w1 (32 m) and w2 (16 m) over own 16 columns
        float p1[32], p2v[16];
        #pragma unroll
        for (int m = 0; m < 32; ++m) p1[m] = 0.f;
        #pragma unroll
        for (int m = 0; m < 16; ++m) p2v[m] = 0.f;
        #pragma unroll 2
        for (int i = 0; i < 16; ++i) {
            float xv = x[i];
            const float* q1 = &s1_q_w[(sub * 16 + i) * 32];
            #pragma unroll
            for (int m = 0; m < 32; ++m) p1[m] = fmaf(xv, q1[m], p1[m]);
            const float* q2 = &s2_q_w[(k * 128 + sub * 16 + i) * 16];
            #pragma unroll
            for (int m = 0; m < 16; ++m) p2v[m] = fmaf(xv, q2[m], p2v[m]);
        }
        // xor-tree reduce across the 8 sub-threads
        #pragma unroll
        for (int mask = 1; mask <= 4; mask <<= 1) {
            #pragma unroll
            for (int m = 0; m < 32; ++m) p1[m] += __shfl_xor(p1[m], mask);
            #pragma unroll
            for (int m = 0; m < 16; ++m) p2v[m] += __shfl_xor(p2v[m], mask);
        }

        // scores for this k at n0, n1 (m ascending, same as round 5)
        float s0 = 0.f, s1v = 0.f;
        #pragma unroll
        for (int m = 0; m < 32; ++m) {
            float w1m = p1[m] + s1_q_b[m];
            s0  = fmaf(r1s[n0 * 33 + m], w1m, s0);
            s1v = fmaf(r1s[n1 * 33 + m], w1m, s1v);
        }
        bv0 = fmaxf(bv0, s0);
        bv1 = fmaxf(bv1, s1v);

        // stash write2 row (+bias)
        #pragma unroll
        for (int m = 0; m < 16; ++m) {
            float v = p2v[m] + s2_q_b[k * 16 + m];
            if (k == 0) w2r0[m] = v; else w2r1[m] = v;
        }
    }

    // operator-slot scores (k = 2)
    {
        const float* wrow = &wops[op * 33];
        float s0 = 0.f, s1v = 0.f;
        #pragma unroll
        for (int m = 0; m < 32; ++m) {
            float wm = wrow[m];
            s0  = fmaf(r1s[n0 * 33 + m], wm, s0);
            s1v = fmaf(r1s[n1 * 33 + m], wm, s1v);
        }
        bv0 = fmaxf(bv0, s0);
        bv1 = fmaxf(bv1, s1v);
    }

    // element-wide argmax over 16 n (first occurrence on ties)
    float bv = bv0; int bn = n0;
    if (bv1 > bv) { bv = bv1; bn = n1; }
    #pragma unroll
    for (int mask = 1; mask <= 4; mask <<= 1) {
        float ov = __shfl_xor(bv, mask);
        int   on = __shfl_xor(bn, mask);
        if (ov > bv || (ov == bv && on < bn)) { bv = ov; bn = on; }
    }
    const int idx_r = bn;

    // attent2 (all 8 threads redundantly; element-local)
    float p20 = 0.f, p21 = 0.f, p22 = 0.f, p23 = 0.f;
    {
        const float* r2a = &r2s[idx_r * 34];        // n=0
        const float* r2b = &r2s[idx_r * 34 + 16];   // n=1
        #pragma unroll
        for (int m = 0; m < 16; ++m) {
            float ra = r2a[m], rb = r2b[m];
            p20 = fmaf(ra, w2r0[m], p20);
            p21 = fmaf(ra, w2r1[m], p21);
            p22 = fmaf(rb, w2r0[m], p22);
            p23 = fmaf(rb, w2r1[m], p23);
        }
    }
    const int idxp = (p21 > p20) ? 1 : 0;
    const int idxc = (p23 > p22) ? 1 : 0;

    // var_h[elem] = [h_p(64) | h_c(64)]  (h recomputed, bitwise-identical)
    {
        const int half = sub >> 2;               // 0 -> p-half, 1 -> c-half
        const int ksel = half ? idxc : idxp;
        const float osel = ksel ? o2 : o1;
        float* dst = &fws[OFF_VARH + (size_t)elem * 128 + sub * 16];
        #pragma unroll
        for (int i4 = 0; i4 < 4; ++i4) {
            float tmp[4];
            #pragma unroll
            for (int q = 0; q < 4; ++q) {
                int j = (sub & 3) * 16 + i4 * 4 + q;
                float bj   = enc_op_b1[j];
                float beff = ksel ? (enc_op_w1[64 + j] + bj) : bj;
                tmp[q] = fmaxf(fmaf(osel, enc_op_w1[j], beff), 0.f);
            }
            float4 v; v.x = tmp[0]; v.y = tmp[1]; v.z = tmp[2]; v.w = tmp[3];
            *(float4*)&dst[i4 * 4] = v;
        }
    }

    // bucketing: LDS histogram -> one padded global atomic per rule
    if (sub == 0) lpos[e] = atomicAdd(&lcnt[idx_r], 1);
    __syncthreads();
    if (t < 16 && lcnt[t] > 0) base[t] = atomicAdd(&cnt[t * 32], lcnt[t]);
    __syncthreads();
    if (sub == 0) bucket[idx_r * B + base[idx_r] + lpos[e]] = elem;
}

// ---------------------------------------------------------------------------
__global__ __launch_bounds__(256) void stage2(
    const float* __restrict__ rule_W2, const float* __restrict__ rule_b2,
    const float* __restrict__ dec_w1,  const float* __restrict__ dec_b1,
    const float* __restrict__ dec_w2,  const float* __restrict__ dec_b2,
    const int* __restrict__ cnt, const int* __restrict__ bucket,
    const float* __restrict__ fws, float* __restrict__ out, int B)
{
    const int rule  = blockIdx.y;
    const int start = blockIdx.x * 32;
    const int count = cnt[rule * 32];
    if (start >= count) return;
    const int nelem = min(32, count - start);
    const int t = threadIdx.x;

    __shared__ float A[32][132];
    __shared__ float H[32][132];
    __shared__ int gi_s[32];

    if (t < 32) gi_s[t] = bucket[rule * B + start + ((t < nelem) ? t : 0)];
    __syncthreads();
    for (int i = t; i < 32 * 32; i += 256) {
        int e = i >> 5, v = i & 31;
        *(float4*)&A[e][v * 4] = *(const float4*)&fws[OFF_VARH + (size_t)gi_s[e] * 128 + v * 4];
    }
    __syncthreads();

    const int colg = t & 15, rowg = t >> 4;

    // GEMM1: H = relu([h_p,h_c](32x128) @ W1h[rule](128x128) + b1h[rule])
    const float* W1  = &fws[OFF_W1H + rule * 16384 + colg * 8];
    const float* b1p = &fws[OFF_B1H + rule * 128 + colg * 8];
    float acc[2][8];
    #pragma unroll
    for (int j = 0; j < 8; ++j) { acc[0][j] = b1p[j]; acc[1][j] = b1p[j]; }
    #pragma unroll 4
    for (int k = 0; k < 128; ++k) {
        float a0 = A[rowg * 2][k], a1 = A[rowg * 2 + 1][k];
        const float4 wa = *(const float4*)&W1[k * 128];
        const float4 wb = *(const float4*)&W1[k * 128 + 4];
        acc[0][0] = fmaf(a0, wa.x, acc[0][0]); acc[1][0] = fmaf(a1, wa.x, acc[1][0]);
        acc[0][1] = fmaf(a0, wa.y, acc[0][1]); acc[1][1] = fmaf(a1, wa.y, acc[1][1]);
        acc[0][2] = fmaf(a0, wa.z, acc[0][2]); acc[1][2] = fmaf(a1, wa.z, acc[1][2]);
        acc[0][3] = fmaf(a0, wa.w, acc[0][3]); acc[1][3] = fmaf(a1, wa.w, acc[1][3]);
        acc[0][4] = fmaf(a0, wb.x, acc[0][4]); acc[1][4] = fmaf(a1, wb.x, acc[1][4]);
        acc[0][5] = fmaf(a0, wb.y, acc[0][5]); acc[1][5] = fmaf(a1, wb.y, acc[1][5]);
        acc[0][6] = fmaf(a0, wb.z, acc[0][6]); acc[1][6] = fmaf(a1, wb.z, acc[1][6]);
        acc[0][7] = fmaf(a0, wb.w, acc[0][7]); acc[1][7] = fmaf(a1, wb.w, acc[1][7]);
    }
    #pragma unroll
    for (int i = 0; i < 2; ++i)
        #pragma unroll
        for (int j = 0; j < 8; ++j)
            H[rowg * 2 + i][colg * 8 + j] = fmaxf(acc[i][j], 0.f);
    __syncthreads();

    // GEMM2: out_all = H(32x128) @ W2[rule](128x128) + b2[rule]
    const float* W2  = &rule_W2[(size_t)rule * 128 * 128 + colg * 8];
    const float* b2p = &rule_b2[rule * 128 + colg * 8];
    #pragma unroll
    for (int j = 0; j < 8; ++j) { acc[0][j] = b2p[j]; acc[1][j] = b2p[j]; }
    #pragma unroll 4
    for (int k = 0; k < 128; ++k) {
        float a0 = H[rowg * 2][k], a1 = H[rowg * 2 + 1][k];
        const float4 wa = *(const float4*)&W2[k * 128];
        const float4 wb = *(const float4*)&W2[k * 128 + 4];
        acc[0][0] = fmaf(a0, wa.x, acc[0][0]); acc[1][0] = fmaf(a1, wa.x, acc[1][0]);
        acc[0][1] = fmaf(a0, wa.y, acc[0][1]); acc[1][1] = fmaf(a1, wa.y, acc[1][1]);
        acc[0][2] = fmaf(a0, wa.z, acc[0][2]); acc[1][2] = fmaf(a1, wa.z, acc[1][2]);
        acc[0][3] = fmaf(a0, wa.w, acc[0][3]); acc[1][3] = fmaf(a1, wa.w, acc[1][3]);
        acc[0][4] = fmaf(a0, wb.x, acc[0][4]); acc[1][4] = fmaf(a1, wb.x, acc[1][4]);
        acc[0][5] = fmaf(a0, wb.y, acc[0][5]); acc[1][5] = fmaf(a1, wb.y, acc[1][5]);
        acc[0][6] = fmaf(a0, wb.z, acc[0][6]); acc[1][6] = fmaf(a1, wb.z, acc[1][6]);
        acc[0][7] = fmaf(a0, wb.w, acc[0][7]); acc[1][7] = fmaf(a1, wb.w, acc[1][7]);
    }
    __syncthreads();   // all A reads done; safe to overwrite
    #pragma unroll
    for (int i = 0; i < 2; ++i)
        #pragma unroll
        for (int j = 0; j < 8; ++j)
            A[rowg * 2 + i][colg * 8 + j] = acc[i][j];
    __syncthreads();

    // decoder: relu(out @ dec_w1 + dec_b1) @ dec_w2 + dec_b2
    const int lane = t & 63;
    const int wv   = t >> 6;
    const int e1   = min(wv * 8 + 8, nelem);
    for (int e = wv * 8; e < e1; ++e) {
        float hd = dec_b1[lane];
        #pragma unroll 8
        for (int d = 0; d < 128; ++d)
            hd = fmaf(A[e][d], dec_w1[d * 64 + lane], hd);
        hd = fmaxf(hd, 0.f);
        float v = hd * dec_w2[lane];
        #pragma unroll
        for (int off = 32; off; off >>= 1) v += __shfl_down(v, off);
        if (lane == 0) out[gi_s[e]] = v + dec_b2[0];
    }
}

// ---------------------------------------------------------------------------
extern "C" void kernel_launch(void* const* d_in, const int* in_sizes, int n_in,
                              void* d_out, int out_size, void* d_ws, size_t ws_size,
                              hipStream_t stream)
{
    const float* op1        = (const float*)d_in[0];
    const float* op2        = (const float*)d_in[1];
    const int*   opr        = (const int*)  d_in[2];
    const float* enc_op_w1  = (const float*)d_in[3];
    const float* enc_op_b1  = (const float*)d_in[4];
    const float* enc_op_w2  = (const float*)d_in[5];
    const float* enc_op_b2  = (const float*)d_in[6];
    const float* enc_opr_w1 = (const float*)d_in[7];
    const float* enc_opr_b1 = (const float*)d_in[8];
    const float* enc_opr_w2 = (const float*)d_in[9];
    const float* enc_opr_b2 = (const float*)d_in[10];
    const float* dec_w1     = (const float*)d_in[11];
    const float* dec_b1     = (const float*)d_in[12];
    const float* dec_w2     = (const float*)d_in[13];
    const float* dec_b2     = (const float*)d_in[14];
    const float* rules_emb  = (const float*)d_in[15];
    const float* rule_W1    = (const float*)d_in[16];
    const float* rule_b1    = (const float*)d_in[17];
    const float* rule_W2    = (const float*)d_in[18];
    const float* rule_b2    = (const float*)d_in[19];
    const float* s1_q_w     = (const float*)d_in[20];
    const float* s1_q_b     = (const float*)d_in[21];
    const float* s1_k_w     = (const float*)d_in[22];
    const float* s1_k_b     = (const float*)d_in[23];
    const float* s2_q_w     = (const float*)d_in[24];
    const float* s2_q_b     = (const float*)d_in[25];
    const float* s2_k_w     = (const float*)d_in[26];
    const float* s2_k_b     = (const float*)d_in[27];

    float* out = (float*)d_out;
    const int B = in_sizes[0];

    int*   cnt    = (int*)d_ws;                 // 16*32 padded counters
    int*   bucket = cnt + 16 * 32;              // 16*B
    float* fws    = (float*)(bucket + 16 * B);  // float region (16B aligned)

    setupB<<<dim3(16, 2), 256, 0, stream>>>(enc_op_w2, enc_op_b2, rule_W1, rule_b1, fws);

    setupA<<<1, 256, 0, stream>>>(
        rules_emb, s1_k_w, s1_k_b, s2_k_w, s2_k_b,
        enc_opr_w1, enc_opr_b1, enc_opr_w2, enc_opr_b2,
        s1_q_w, s1_q_b, cnt, fws);

    stage1<<<B / 32, 256, 0, stream>>>(
        op1, op2, opr, enc_op_w1, enc_op_b1, enc_op_w2, enc_op_b2,
        s1_q_w, s1_q_b, s2_q_w, s2_q_b, cnt, bucket, fws, B);

    stage2<<<dim3(B / 32, 16), 256, 0, stream>>>(
        rule_W2, rule_b2, dec_w1, dec_b1, dec_w2, dec_b2,
        cnt, bucket, fws, out, B);
}

// Round 9
// 180.535 us; speedup vs baseline: 1.6329x; 1.6329x over previous
//
#include <hip/hip_runtime.h>
#include <math.h>

// ---------------------------------------------------------------------------
// ArithmeticNps: B=16384, CV=128, CR=64, NR=16, CM_RULE=128
// Key algebra: attent1/attent2 feed ONLY argmax, and are linear in the 64-dim
// encoder hiddens h1,h2. Fold everything once in setup:
//   score(n,k)   = t1[n] + h_k . S1[n][:]         (k<2);  t1op[op][n] (k=2)
//   attent2(nk)  = u2[nk][r] + h_k . V2[nk][:][r]
// (scales 1/sqrt(32), 1/sqrt(16) dropped — argmax-invariant.)
// stage1 per elem: h (128 relu-fma) + 36 64-dots. No x, no shuffles.
// setup fuses: blocks 0..31 = W1h fold (w2 @ rule_W1), block 32 = tables.
// stage2 unchanged from the passing round-5/7 kernel.
// ---------------------------------------------------------------------------

#define OFF_S1    0        // 16*64 = 1024
#define OFF_T1    1024     // 16
#define OFF_T1OP  1040     // 48 (pad to 64)
#define OFF_U2    1104     // 64
#define OFF_V2    1168     // 4*64*16 = 4096
#define OFF_W1H   5264     // 16*128*128 = 262144
#define OFF_B1H   267408   // 16*128 = 2048
#define OFF_VARH  269456   // B*128

// ---------------------------------------------------------------------------
// grid (33, 2): blockIdx.x<32 -> W1h fold tile (r = bx>>1, half = bx&1);
// blockIdx.x==32 && y==0 -> table precompute. y==1 idles for x==32.
__global__ __launch_bounds__(256) void setup_fused(
    const float* __restrict__ rules_emb, const float* __restrict__ s1_k_w,
    const float* __restrict__ s1_k_b,   const float* __restrict__ s2_k_w,
    const float* __restrict__ s2_k_b,
    const float* __restrict__ enc_opr_w1, const float* __restrict__ enc_opr_b1,
    const float* __restrict__ enc_opr_w2, const float* __restrict__ enc_opr_b2,
    const float* __restrict__ enc_op_w2,  const float* __restrict__ enc_op_b2,
    const float* __restrict__ s1_q_w, const float* __restrict__ s1_q_b,
    const float* __restrict__ s2_q_w, const float* __restrict__ s2_q_b,
    const float* __restrict__ rule_W1, const float* __restrict__ rule_b1,
    int* __restrict__ cnt, float* __restrict__ fws)
{
    const int t = threadIdx.x;

    if (blockIdx.x < 32) {
        if (blockIdx.y != 0) return;
        // ---- W1h[r][half*64+j][m] = sum_c w2[j][c] * rule_W1[r][half*128+c][m]
        const int r = blockIdx.x >> 1, half = blockIdx.x & 1;
        const int colg = t & 15, rowg = t >> 4;
        const float* W1src = &rule_W1[((size_t)r * 256 + half * 128) * 128];

        float acc[4][8];
        #pragma unroll
        for (int i = 0; i < 4; ++i)
            #pragma unroll
            for (int j = 0; j < 8; ++j) acc[i][j] = 0.f;

        #pragma unroll 2
        for (int c = 0; c < 128; ++c) {
            const float4 wa = *(const float4*)&W1src[c * 128 + colg * 8];
            const float4 wb = *(const float4*)&W1src[c * 128 + colg * 8 + 4];
            #pragma unroll
            for (int i = 0; i < 4; ++i) {
                float w = enc_op_w2[(rowg * 4 + i) * 128 + c];
                acc[i][0] = fmaf(w, wa.x, acc[i][0]); acc[i][1] = fmaf(w, wa.y, acc[i][1]);
                acc[i][2] = fmaf(w, wa.z, acc[i][2]); acc[i][3] = fmaf(w, wa.w, acc[i][3]);
                acc[i][4] = fmaf(w, wb.x, acc[i][4]); acc[i][5] = fmaf(w, wb.y, acc[i][5]);
                acc[i][6] = fmaf(w, wb.z, acc[i][6]); acc[i][7] = fmaf(w, wb.w, acc[i][7]);
            }
        }
        #pragma unroll
        for (int i = 0; i < 4; ++i)
            #pragma unroll
            for (int j = 0; j < 8; ++j)
                fws[OFF_W1H + r * 16384 + (half * 64 + rowg * 4 + i) * 128 + colg * 8 + j] = acc[i][j];

        if (half == 0 && t < 128) {
            const float* W1r = &rule_W1[(size_t)r * 256 * 128];
            float b = rule_b1[r * 128 + t];
            for (int c = 0; c < 128; ++c)
                b += enc_op_b2[c] * (W1r[c * 128 + t] + W1r[(128 + c) * 128 + t]);
            fws[OFF_B1H + r * 128 + t] = b;
        }
        return;
    }
    if (blockIdx.y != 0) return;

    // ---- table precompute (one block) ----
    if (t < 16) cnt[t * 32] = 0;   // padded counters

    __shared__ float ope_s[3 * 128];
    __shared__ float read1_s[512];
    __shared__ float read2_s[512];
    __shared__ float c1_s[32];
    __shared__ float c2_s[32];
    __shared__ float w1ope_s[96];
    __shared__ float M1_s[64 * 32];
    __shared__ float M2_s[2 * 64 * 16];

    for (int idx = t; idx < 3 * 128; idx += 256) {
        int v = idx >> 7, c = idx & 127;
        float o = enc_opr_b2[c];
        for (int j = 0; j < 64; ++j) {
            float h = fmaxf(enc_opr_w1[v * 64 + j] + enc_opr_b1[j], 0.f);
            o = fmaf(h, enc_opr_w2[j * 128 + c], o);
        }
        ope_s[idx] = o;
    }
    for (int idx = t; idx < 512; idx += 256) {
        int n = idx >> 5;
        float a = s1_k_b[idx];
        for (int r = 0; r < 64; ++r)
            a = fmaf(rules_emb[n * 64 + r], s1_k_w[(n * 64 + r) * 32 + (idx & 31)], a);
        read1_s[idx] = a;
    }
    for (int idx = t; idx < 512; idx += 256) {
        int r = idx >> 5, n = (idx >> 4) & 1, m = idx & 15;
        float a = s2_k_b[n * 16 + m];
        for (int j = 0; j < 64; ++j)
            a = fmaf(rules_emb[r * 64 + j], s2_k_w[(n * 64 + j) * 16 + m], a);
        read2_s[idx] = a;
    }
    for (int idx = t; idx < 32; idx += 256) {
        float a = s1_q_b[idx];
        for (int c = 0; c < 128; ++c)
            a = fmaf(enc_op_b2[c], s1_q_w[c * 32 + idx], a);
        c1_s[idx] = a;
    }
    for (int idx = t; idx < 32; idx += 256) {
        int k = idx >> 4, m = idx & 15;
        float a = s2_q_b[idx];
        for (int c = 0; c < 128; ++c)
            a = fmaf(enc_op_b2[c], s2_q_w[(k * 128 + c) * 16 + m], a);
        c2_s[idx] = a;
    }
    for (int idx = t; idx < 2048; idx += 256) {       // M1[j][m]
        int j = idx >> 5, m = idx & 31;
        float a = 0.f;
        for (int c = 0; c < 128; ++c)
            a = fmaf(enc_op_w2[j * 128 + c], s1_q_w[c * 32 + m], a);
        M1_s[idx] = a;
    }
    for (int idx = t; idx < 2048; idx += 256) {       // M2[k][j][m]
        int k = idx >> 10, j = (idx >> 4) & 63, m = idx & 15;
        float a = 0.f;
        for (int c = 0; c < 128; ++c)
            a = fmaf(enc_op_w2[j * 128 + c], s2_q_w[(k * 128 + c) * 16 + m], a);
        M2_s[idx] = a;
    }
    __syncthreads();
    for (int idx = t; idx < 96; idx += 256) {         // w1ope[v][m]
        int v = idx >> 5, m = idx & 31;
        float a = s1_q_b[m];
        for (int c = 0; c < 128; ++c)
            a = fmaf(ope_s[v * 128 + c], s1_q_w[c * 32 + m], a);
        w1ope_s[idx] = a;
    }
    __syncthreads();
    for (int idx = t; idx < 1024; idx += 256) {       // S1[n][j]
        int n = idx >> 6, j = idx & 63;
        float a = 0.f;
        for (int m = 0; m < 32; ++m)
            a = fmaf(read1_s[n * 32 + m], M1_s[j * 32 + m], a);
        fws[OFF_S1 + idx] = a;
    }
    for (int idx = t; idx < 16; idx += 256) {         // t1[n]
        float a = 0.f;
        for (int m = 0; m < 32; ++m)
            a = fmaf(read1_s[idx * 32 + m], c1_s[m], a);
        fws[OFF_T1 + idx] = a;
    }
    for (int idx = t; idx < 48; idx += 256) {         // t1op[v][n]
        int v = idx / 16, n = idx % 16;
        float a = 0.f;
        for (int m = 0; m < 32; ++m)
            a = fmaf(read1_s[n * 32 + m], w1ope_s[v * 32 + m], a);
        fws[OFF_T1OP + idx] = a;
    }
    for (int idx = t; idx < 64; idx += 256) {         // u2[nk][r]
        int nk = idx >> 4, r = idx & 15, n = nk >> 1, k = nk & 1;
        float a = 0.f;
        for (int m = 0; m < 16; ++m)
            a = fmaf(read2_s[r * 32 + n * 16 + m], c2_s[k * 16 + m], a);
        fws[OFF_U2 + idx] = a;
    }
    for (int idx = t; idx < 4096; idx += 256) {       // V2[nk][j][r]
        int nk = idx >> 10, j = (idx >> 4) & 63, r = idx & 15;
        int n = nk >> 1, k = nk & 1;
        float a = 0.f;
        for (int m = 0; m < 16; ++m)
            a = fmaf(read2_s[r * 32 + n * 16 + m], M2_s[(k * 64 + j) * 16 + m], a);
        fws[OFF_V2 + idx] = a;
    }
}

// ---------------------------------------------------------------------------
__global__ __launch_bounds__(256) void stage1(
    const float* __restrict__ op1, const float* __restrict__ op2,
    const int* __restrict__ opr,
    const float* __restrict__ enc_op_w1, const float* __restrict__ enc_op_b1,
    int* __restrict__ cnt, int* __restrict__ bucket,
    float* __restrict__ fws, int B)
{
    const int t = threadIdx.x;
    const int blk = blockIdx.x;

    __shared__ float S1s[16 * 68];    // S1[n][j], padded row 68 (float4-able)
    __shared__ float h[32][132];      // [e][k*64+j]
    __shared__ float t1s[16];
    __shared__ float t1ops[48];
    __shared__ float u2s[64];
    __shared__ float bvaln[32][17];
    __shared__ float part2[4][32];
    __shared__ float o1s[32], o2s[32];
    __shared__ int ops_[32], idxr[32], idxp[32], idxc[32];
    __shared__ int lcnt[16], lpos[32], base[16];

    if (t < 32) { o1s[t] = op1[blk * 32 + t]; o2s[t] = op2[blk * 32 + t]; ops_[t] = opr[blk * 32 + t]; }
    if (t < 16) { lcnt[t] = 0; t1s[t] = fws[OFF_T1 + t]; }
    if (t >= 16 && t < 64)  t1ops[t - 16] = fws[OFF_T1OP + (t - 16)];
    if (t >= 64 && t < 128) u2s[t - 64]   = fws[OFF_U2 + (t - 64)];
    for (int i = t; i < 1024; i += 256) S1s[(i >> 6) * 68 + (i & 63)] = fws[OFF_S1 + i];
    __syncthreads();

    // encoder hiddens h[e][k*64+j] (same per-value expression as r5/r7)
    for (int i = t; i < 4096; i += 256) {
        int e = i >> 7, j = i & 127;
        if (j < 64) {
            h[e][j] = fmaxf(fmaf(o1s[e], enc_op_w1[j], enc_op_b1[j]), 0.f);
        } else {
            int j2 = j - 64;
            h[e][j] = fmaxf(fmaf(o2s[e], enc_op_w1[j2], enc_op_w1[64 + j2] + enc_op_b1[j2]), 0.f);
        }
    }
    __syncthreads();

    // scores: pair p = (e,n); bvaln[e][n] = max over the 3 slots
    #pragma unroll
    for (int pp = 0; pp < 2; ++pp) {
        int p = t + pp * 256;
        int e = p >> 4, n = p & 15;
        float a0 = 0.f, a1 = 0.f;
        #pragma unroll 4
        for (int j4 = 0; j4 < 16; ++j4) {
            float4 s  = *(const float4*)&S1s[n * 68 + j4 * 4];
            float4 h0 = *(const float4*)&h[e][j4 * 4];
            float4 h1 = *(const float4*)&h[e][64 + j4 * 4];
            a0 = fmaf(h0.x, s.x, a0); a0 = fmaf(h0.y, s.y, a0);
            a0 = fmaf(h0.z, s.z, a0); a0 = fmaf(h0.w, s.w, a0);
            a1 = fmaf(h1.x, s.x, a1); a1 = fmaf(h1.y, s.y, a1);
            a1 = fmaf(h1.z, s.z, a1); a1 = fmaf(h1.w, s.w, a1);
        }
        bvaln[e][n] = fmaxf(t1s[n] + fmaxf(a0, a1), t1ops[ops_[e] * 16 + n]);
    }
    __syncthreads();

    // per-element argmax over n (strict >, ascending = first occurrence)
    if (t < 32) {
        float best = -INFINITY; int bn = 0;
        for (int n = 0; n < 16; ++n) {
            float v = bvaln[t][n];
            if (v > best) { best = v; bn = n; }
        }
        idxr[t] = bn;
    }
    __syncthreads();

    // attent2: thread (e, nk): u2[nk][r] + h_k . V2[nk][:][r]
    if (t < 128) {
        const int e = t & 31, nk = t >> 5, k = nk & 1;
        const int r = idxr[e];
        const float* v2p = &fws[OFF_V2 + nk * 1024 + r];
        float a = 0.f;
        #pragma unroll 4
        for (int j = 0; j < 64; ++j)
            a = fmaf(h[e][k * 64 + j], v2p[j * 16], a);
        part2[nk][e] = a + u2s[nk * 16 + r];
    }
    __syncthreads();
    if (t < 32) {
        idxp[t] = (part2[1][t] > part2[0][t]) ? 1 : 0;
        idxc[t] = (part2[3][t] > part2[2][t]) ? 1 : 0;
    }
    __syncthreads();

    // var_h[elem] = [h_p(64) | h_c(64)]
    for (int i = t; i < 1024; i += 256) {
        int e = i >> 5, v4 = i & 31;
        int sel = (v4 < 16) ? idxp[e] : idxc[e];
        float4 val = *(const float4*)&h[e][sel * 64 + (v4 & 15) * 4];
        *(float4*)&fws[OFF_VARH + (size_t)(blk * 32 + e) * 128 + v4 * 4] = val;
    }

    // bucketing: LDS histogram -> one padded global atomic per rule
    if (t < 32) lpos[t] = atomicAdd(&lcnt[idxr[t]], 1);
    __syncthreads();
    if (t < 16 && lcnt[t] > 0) base[t] = atomicAdd(&cnt[t * 32], lcnt[t]);
    __syncthreads();
    if (t < 32) {
        int r = idxr[t];
        bucket[r * B + base[r] + lpos[t]] = blk * 32 + t;
    }
}

// ---------------------------------------------------------------------------
__global__ __launch_bounds__(256) void stage2(
    const float* __restrict__ rule_W2, const float* __restrict__ rule_b2,
    const float* __restrict__ dec_w1,  const float* __restrict__ dec_b1,
    const float* __restrict__ dec_w2,  const float* __restrict__ dec_b2,
    const int* __restrict__ cnt, const int* __restrict__ bucket,
    const float* __restrict__ fws, float* __restrict__ out, int B)
{
    const int rule  = blockIdx.y;
    const int start = blockIdx.x * 32;
    const int count = cnt[rule * 32];
    if (start >= count) return;
    const int nelem = min(32, count - start);
    const int t = threadIdx.x;

    __shared__ float A[32][132];
    __shared__ float H[32][132];
    __shared__ int gi_s[32];

    if (t < 32) gi_s[t] = bucket[rule * B + start + ((t < nelem) ? t : 0)];
    __syncthreads();
    for (int i = t; i < 32 * 32; i += 256) {
        int e = i >> 5, v = i & 31;
        *(float4*)&A[e][v * 4] = *(const float4*)&fws[OFF_VARH + (size_t)gi_s[e] * 128 + v * 4];
    }
    __syncthreads();

    const int colg = t & 15, rowg = t >> 4;

    // GEMM1: H = relu([h_p,h_c](32x128) @ W1h[rule](128x128) + b1h[rule])
    const float* W1  = &fws[OFF_W1H + rule * 16384 + colg * 8];
    const float* b1p = &fws[OFF_B1H + rule * 128 + colg * 8];
    float acc[2][8];
    #pragma unroll
    for (int j = 0; j < 8; ++j) { acc[0][j] = b1p[j]; acc[1][j] = b1p[j]; }
    #pragma unroll 4
    for (int k = 0; k < 128; ++k) {
        float a0 = A[rowg * 2][k], a1 = A[rowg * 2 + 1][k];
        const float4 wa = *(const float4*)&W1[k * 128];
        const float4 wb = *(const float4*)&W1[k * 128 + 4];
        acc[0][0] = fmaf(a0, wa.x, acc[0][0]); acc[1][0] = fmaf(a1, wa.x, acc[1][0]);
        acc[0][1] = fmaf(a0, wa.y, acc[0][1]); acc[1][1] = fmaf(a1, wa.y, acc[1][1]);
        acc[0][2] = fmaf(a0, wa.z, acc[0][2]); acc[1][2] = fmaf(a1, wa.z, acc[1][2]);
        acc[0][3] = fmaf(a0, wa.w, acc[0][3]); acc[1][3] = fmaf(a1, wa.w, acc[1][3]);
        acc[0][4] = fmaf(a0, wb.x, acc[0][4]); acc[1][4] = fmaf(a1, wb.x, acc[1][4]);
        acc[0][5] = fmaf(a0, wb.y, acc[0][5]); acc[1][5] = fmaf(a1, wb.y, acc[1][5]);
        acc[0][6] = fmaf(a0, wb.z, acc[0][6]); acc[1][6] = fmaf(a1, wb.z, acc[1][6]);
        acc[0][7] = fmaf(a0, wb.w, acc[0][7]); acc[1][7] = fmaf(a1, wb.w, acc[1][7]);
    }
    #pragma unroll
    for (int i = 0; i < 2; ++i)
        #pragma unroll
        for (int j = 0; j < 8; ++j)
            H[rowg * 2 + i][colg * 8 + j] = fmaxf(acc[i][j], 0.f);
    __syncthreads();

    // GEMM2: out_all = H(32x128) @ W2[rule](128x128) + b2[rule]
    const float* W2  = &rule_W2[(size_t)rule * 128 * 128 + colg * 8];
    const float* b2p = &rule_b2[rule * 128 + colg * 8];
    #pragma unroll
    for (int j = 0; j < 8; ++j) { acc[0][j] = b2p[j]; acc[1][j] = b2p[j]; }
    #pragma unroll 4
    for (int k = 0; k < 128; ++k) {
        float a0 = H[rowg * 2][k], a1 = H[rowg * 2 + 1][k];
        const float4 wa = *(const float4*)&W2[k * 128];
        const float4 wb = *(const float4*)&W2[k * 128 + 4];
        acc[0][0] = fmaf(a0, wa.x, acc[0][0]); acc[1][0] = fmaf(a1, wa.x, acc[1][0]);
        acc[0][1] = fmaf(a0, wa.y, acc[0][1]); acc[1][1] = fmaf(a1, wa.y, acc[1][1]);
        acc[0][2] = fmaf(a0, wa.z, acc[0][2]); acc[1][2] = fmaf(a1, wa.z, acc[1][2]);
        acc[0][3] = fmaf(a0, wa.w, acc[0][3]); acc[1][3] = fmaf(a1, wa.w, acc[1][3]);
        acc[0][4] = fmaf(a0, wb.x, acc[0][4]); acc[1][4] = fmaf(a1, wb.x, acc[1][4]);
        acc[0][5] = fmaf(a0, wb.y, acc[0][5]); acc[1][5] = fmaf(a1, wb.y, acc[1][5]);
        acc[0][6] = fmaf(a0, wb.z, acc[0][6]); acc[1][6] = fmaf(a1, wb.z, acc[1][6]);
        acc[0][7] = fmaf(a0, wb.w, acc[0][7]); acc[1][7] = fmaf(a1, wb.w, acc[1][7]);
    }
    __syncthreads();
    #pragma unroll
    for (int i = 0; i < 2; ++i)
        #pragma unroll
        for (int j = 0; j < 8; ++j)
            A[rowg * 2 + i][colg * 8 + j] = acc[i][j];
    __syncthreads();

    // decoder
    const int lane = t & 63;
    const int wv   = t >> 6;
    const int e1   = min(wv * 8 + 8, nelem);
    for (int e = wv * 8; e < e1; ++e) {
        float hd = dec_b1[lane];
        #pragma unroll 8
        for (int d = 0; d < 128; ++d)
            hd = fmaf(A[e][d], dec_w1[d * 64 + lane], hd);
        hd = fmaxf(hd, 0.f);
        float v = hd * dec_w2[lane];
        #pragma unroll
        for (int off = 32; off; off >>= 1) v += __shfl_down(v, off);
        if (lane == 0) out[gi_s[e]] = v + dec_b2[0];
    }
}

// ---------------------------------------------------------------------------
extern "C" void kernel_launch(void* const* d_in, const int* in_sizes, int n_in,
                              void* d_out, int out_size, void* d_ws, size_t ws_size,
                              hipStream_t stream)
{
    const float* op1        = (const float*)d_in[0];
    const float* op2        = (const float*)d_in[1];
    const int*   opr        = (const int*)  d_in[2];
    const float* enc_op_w1  = (const float*)d_in[3];
    const float* enc_op_b1  = (const float*)d_in[4];
    const float* enc_op_w2  = (const float*)d_in[5];
    const float* enc_op_b2  = (const float*)d_in[6];
    const float* enc_opr_w1 = (const float*)d_in[7];
    const float* enc_opr_b1 = (const float*)d_in[8];
    const float* enc_opr_w2 = (const float*)d_in[9];
    const float* enc_opr_b2 = (const float*)d_in[10];
    const float* dec_w1     = (const float*)d_in[11];
    const float* dec_b1     = (const float*)d_in[12];
    const float* dec_w2     = (const float*)d_in[13];
    const float* dec_b2     = (const float*)d_in[14];
    const float* rules_emb  = (const float*)d_in[15];
    const float* rule_W1    = (const float*)d_in[16];
    const float* rule_b1    = (const float*)d_in[17];
    const float* rule_W2    = (const float*)d_in[18];
    const float* rule_b2    = (const float*)d_in[19];
    const float* s1_q_w     = (const float*)d_in[20];
    const float* s1_q_b     = (const float*)d_in[21];
    const float* s1_k_w     = (const float*)d_in[22];
    const float* s1_k_b     = (const float*)d_in[23];
    const float* s2_q_w     = (const float*)d_in[24];
    const float* s2_q_b     = (const float*)d_in[25];
    const float* s2_k_w     = (const float*)d_in[26];
    const float* s2_k_b     = (const float*)d_in[27];

    float* out = (float*)d_out;
    const int B = in_sizes[0];

    int*   cnt    = (int*)d_ws;                 // 16*32 padded counters
    int*   bucket = cnt + 16 * 32;              // 16*B
    float* fws    = (float*)(bucket + 16 * B);  // float region (16B aligned)

    setup_fused<<<dim3(33, 2), 256, 0, stream>>>(
        rules_emb, s1_k_w, s1_k_b, s2_k_w, s2_k_b,
        enc_opr_w1, enc_opr_b1, enc_opr_w2, enc_opr_b2,
        enc_op_w2, enc_op_b2, s1_q_w, s1_q_b, s2_q_w, s2_q_b,
        rule_W1, rule_b1, cnt, fws);

    stage1<<<B / 32, 256, 0, stream>>>(
        op1, op2, opr, enc_op_w1, enc_op_b1, cnt, bucket, fws, B);

    stage2<<<dim3(B / 32, 16), 256, 0, stream>>>(
        rule_W2, rule_b2, dec_w1, dec_b1, dec_w2, dec_b2,
        cnt, bucket, fws, out, B);
}

// Round 11
// 130.390 us; speedup vs baseline: 2.2608x; 1.3846x over previous
//
#include <hip/hip_runtime.h>
#include <math.h>

// ---------------------------------------------------------------------------
// ArithmeticNps: B=16384, CV=128, CR=64, NR=16, CM_RULE=128
// Algebra (all argmax-invariant or continuous-path):
//   stage1 scores: score(n,k) = t1[n] + h_k.S1[n][:], t1op[op][n] (k=2);
//                  attent2(nk) = u2[nk][r] + h_k.V2[nk][:][r]
//   stage2: W1h[r] = w2 @ rule_W1[r]  (K: 256->128, folds encoder w2)
//           W2d[r] = rule_W2[r] @ dec_w1 (128x64, folds decoder layer 1!)
//           x3 = relu( relu([h_p,h_c]@W1h+b1h) @ W2d + b2d ) . dec_w2 + dec_b2
// stage2: 64 elems/block -> 2x FMA density per weight load, no serial
// decoder chain. stage1 unchanged from passing round 9.
// ---------------------------------------------------------------------------

#define OFF_S1    0        // 1024
#define OFF_T1    1024     // 16
#define OFF_T1OP  1040     // 64
#define OFF_U2    1104     // 64
#define OFF_V2    1168     // 4096
#define OFF_W1H   5264     // 16*128*128 = 262144
#define OFF_B1H   267408   // 2048
#define OFF_W2D   269456   // 16*128*64 = 131072
#define OFF_B2D   400528   // 1024
#define OFF_VARH  401552   // B*128

// ---------------------------------------------------------------------------
// grid (49): bx<32 -> W1h fold; 32<=bx<48 -> W2d fold; bx==48 -> tables.
__global__ __launch_bounds__(256) void setup_fused(
    const float* __restrict__ rules_emb, const float* __restrict__ s1_k_w,
    const float* __restrict__ s1_k_b,   const float* __restrict__ s2_k_w,
    const float* __restrict__ s2_k_b,
    const float* __restrict__ enc_opr_w1, const float* __restrict__ enc_opr_b1,
    const float* __restrict__ enc_opr_w2, const float* __restrict__ enc_opr_b2,
    const float* __restrict__ enc_op_w2,  const float* __restrict__ enc_op_b2,
    const float* __restrict__ s1_q_w, const float* __restrict__ s1_q_b,
    const float* __restrict__ s2_q_w, const float* __restrict__ s2_q_b,
    const float* __restrict__ rule_W1, const float* __restrict__ rule_b1,
    const float* __restrict__ rule_W2, const float* __restrict__ rule_b2,
    const float* __restrict__ dec_w1,  const float* __restrict__ dec_b1,
    int* __restrict__ cnt, float* __restrict__ fws)
{
    const int t = threadIdx.x;

    if (blockIdx.x < 32) {
        // ---- W1h[r][half*64+j][m] = sum_c w2[j][c] * rule_W1[r][half*128+c][m]
        const int r = blockIdx.x >> 1, half = blockIdx.x & 1;
        const int colg = t & 15, rowg = t >> 4;
        const float* W1src = &rule_W1[((size_t)r * 256 + half * 128) * 128];

        float acc[4][8];
        #pragma unroll
        for (int i = 0; i < 4; ++i)
            #pragma unroll
            for (int j = 0; j < 8; ++j) acc[i][j] = 0.f;

        #pragma unroll 2
        for (int c = 0; c < 128; ++c) {
            const float4 wa = *(const float4*)&W1src[c * 128 + colg * 8];
            const float4 wb = *(const float4*)&W1src[c * 128 + colg * 8 + 4];
            #pragma unroll
            for (int i = 0; i < 4; ++i) {
                float w = enc_op_w2[(rowg * 4 + i) * 128 + c];
                acc[i][0] = fmaf(w, wa.x, acc[i][0]); acc[i][1] = fmaf(w, wa.y, acc[i][1]);
                acc[i][2] = fmaf(w, wa.z, acc[i][2]); acc[i][3] = fmaf(w, wa.w, acc[i][3]);
                acc[i][4] = fmaf(w, wb.x, acc[i][4]); acc[i][5] = fmaf(w, wb.y, acc[i][5]);
                acc[i][6] = fmaf(w, wb.z, acc[i][6]); acc[i][7] = fmaf(w, wb.w, acc[i][7]);
            }
        }
        #pragma unroll
        for (int i = 0; i < 4; ++i)
            #pragma unroll
            for (int j = 0; j < 8; ++j)
                fws[OFF_W1H + r * 16384 + (half * 64 + rowg * 4 + i) * 128 + colg * 8 + j] = acc[i][j];

        if (half == 0 && t < 128) {
            const float* W1r = &rule_W1[(size_t)r * 256 * 128];
            float b = rule_b1[r * 128 + t];
            for (int c = 0; c < 128; ++c)
                b += enc_op_b2[c] * (W1r[c * 128 + t] + W1r[(128 + c) * 128 + t]);
            fws[OFF_B1H + r * 128 + t] = b;
        }
        return;
    }

    if (blockIdx.x < 48) {
        // ---- W2d[r][d][q] = sum_c rule_W2[r][d][c] * dec_w1[c][q]
        const int r = blockIdx.x - 32;
        const int colg = t & 7, rowg = t >> 3;    // q = colg*8..+8, d = rowg*4..+4
        const float* W2r = &rule_W2[(size_t)r * 128 * 128];

        float acc[4][8];
        #pragma unroll
        for (int i = 0; i < 4; ++i)
            #pragma unroll
            for (int j = 0; j < 8; ++j) acc[i][j] = 0.f;

        #pragma unroll 2
        for (int c = 0; c < 128; ++c) {
            const float4 da = *(const float4*)&dec_w1[c * 64 + colg * 8];
            const float4 db = *(const float4*)&dec_w1[c * 64 + colg * 8 + 4];
            #pragma unroll
            for (int i = 0; i < 4; ++i) {
                float w = W2r[(rowg * 4 + i) * 128 + c];
                acc[i][0] = fmaf(w, da.x, acc[i][0]); acc[i][1] = fmaf(w, da.y, acc[i][1]);
                acc[i][2] = fmaf(w, da.z, acc[i][2]); acc[i][3] = fmaf(w, da.w, acc[i][3]);
                acc[i][4] = fmaf(w, db.x, acc[i][4]); acc[i][5] = fmaf(w, db.y, acc[i][5]);
                acc[i][6] = fmaf(w, db.z, acc[i][6]); acc[i][7] = fmaf(w, db.w, acc[i][7]);
            }
        }
        #pragma unroll
        for (int i = 0; i < 4; ++i)
            #pragma unroll
            for (int j = 0; j < 8; ++j)
                fws[OFF_W2D + r * 8192 + (rowg * 4 + i) * 64 + colg * 8 + j] = acc[i][j];

        // b2d[r][q] = dec_b1[q] + sum_c b2[r][c] * dec_w1[c][q]
        if (t < 64) {
            float b = dec_b1[t];
            for (int c = 0; c < 128; ++c)
                b = fmaf(rule_b2[r * 128 + c], dec_w1[c * 64 + t], b);
            fws[OFF_B2D + r * 64 + t] = b;
        }
        return;
    }

    // ---- table precompute (one block) ----
    if (t < 16) cnt[t * 32] = 0;   // padded counters

    __shared__ float ope_s[3 * 128];
    __shared__ float read1_s[512];
    __shared__ float read2_s[512];
    __shared__ float c1_s[32];
    __shared__ float c2_s[32];
    __shared__ float w1ope_s[96];
    __shared__ float M1_s[64 * 32];
    __shared__ float M2_s[2 * 64 * 16];

    for (int idx = t; idx < 3 * 128; idx += 256) {
        int v = idx >> 7, c = idx & 127;
        float o = enc_opr_b2[c];
        for (int j = 0; j < 64; ++j) {
            float h = fmaxf(enc_opr_w1[v * 64 + j] + enc_opr_b1[j], 0.f);
            o = fmaf(h, enc_opr_w2[j * 128 + c], o);
        }
        ope_s[idx] = o;
    }
    for (int idx = t; idx < 512; idx += 256) {
        int n = idx >> 5;
        float a = s1_k_b[idx];
        for (int r = 0; r < 64; ++r)
            a = fmaf(rules_emb[n * 64 + r], s1_k_w[(n * 64 + r) * 32 + (idx & 31)], a);
        read1_s[idx] = a;
    }
    for (int idx = t; idx < 512; idx += 256) {
        int r = idx >> 5, n = (idx >> 4) & 1, m = idx & 15;
        float a = s2_k_b[n * 16 + m];
        for (int j = 0; j < 64; ++j)
            a = fmaf(rules_emb[r * 64 + j], s2_k_w[(n * 64 + j) * 16 + m], a);
        read2_s[idx] = a;
    }
    for (int idx = t; idx < 32; idx += 256) {
        float a = s1_q_b[idx];
        for (int c = 0; c < 128; ++c)
            a = fmaf(enc_op_b2[c], s1_q_w[c * 32 + idx], a);
        c1_s[idx] = a;
    }
    for (int idx = t; idx < 32; idx += 256) {
        int k = idx >> 4, m = idx & 15;
        float a = s2_q_b[idx];
        for (int c = 0; c < 128; ++c)
            a = fmaf(enc_op_b2[c], s2_q_w[(k * 128 + c) * 16 + m], a);
        c2_s[idx] = a;
    }
    for (int idx = t; idx < 2048; idx += 256) {       // M1[j][m]
        int j = idx >> 5, m = idx & 31;
        float a = 0.f;
        for (int c = 0; c < 128; ++c)
            a = fmaf(enc_op_w2[j * 128 + c], s1_q_w[c * 32 + m], a);
        M1_s[idx] = a;
    }
    for (int idx = t; idx < 2048; idx += 256) {       // M2[k][j][m]
        int k = idx >> 10, j = (idx >> 4) & 63, m = idx & 15;
        float a = 0.f;
        for (int c = 0; c < 128; ++c)
            a = fmaf(enc_op_w2[j * 128 + c], s2_q_w[(k * 128 + c) * 16 + m], a);
        M2_s[idx] = a;
    }
    __syncthreads();
    for (int idx = t; idx < 96; idx += 256) {         // w1ope[v][m]
        int v = idx >> 5, m = idx & 31;
        float a = s1_q_b[m];
        for (int c = 0; c < 128; ++c)
            a = fmaf(ope_s[v * 128 + c], s1_q_w[c * 32 + m], a);
        w1ope_s[idx] = a;
    }
    __syncthreads();
    for (int idx = t; idx < 1024; idx += 256) {       // S1[n][j]
        int n = idx >> 6, j = idx & 63;
        float a = 0.f;
        for (int m = 0; m < 32; ++m)
            a = fmaf(read1_s[n * 32 + m], M1_s[j * 32 + m], a);
        fws[OFF_S1 + idx] = a;
    }
    for (int idx = t; idx < 16; idx += 256) {         // t1[n]
        float a = 0.f;
        for (int m = 0; m < 32; ++m)
            a = fmaf(read1_s[idx * 32 + m], c1_s[m], a);
        fws[OFF_T1 + idx] = a;
    }
    for (int idx = t; idx < 48; idx += 256) {         // t1op[v][n]
        int v = idx / 16, n = idx % 16;
        float a = 0.f;
        for (int m = 0; m < 32; ++m)
            a = fmaf(read1_s[n * 32 + m], w1ope_s[v * 32 + m], a);
        fws[OFF_T1OP + idx] = a;
    }
    for (int idx = t; idx < 64; idx += 256) {         // u2[nk][r]
        int nk = idx >> 4, r = idx & 15, n = nk >> 1, k = nk & 1;
        float a = 0.f;
        for (int m = 0; m < 16; ++m)
            a = fmaf(read2_s[r * 32 + n * 16 + m], c2_s[k * 16 + m], a);
        fws[OFF_U2 + idx] = a;
    }
    for (int idx = t; idx < 4096; idx += 256) {       // V2[nk][j][r]
        int nk = idx >> 10, j = (idx >> 4) & 63, r = idx & 15;
        int n = nk >> 1, k = nk & 1;
        float a = 0.f;
        for (int m = 0; m < 16; ++m)
            a = fmaf(read2_s[r * 32 + n * 16 + m], M2_s[(k * 64 + j) * 16 + m], a);
        fws[OFF_V2 + idx] = a;
    }
}

// ---------------------------------------------------------------------------
__global__ __launch_bounds__(256) void stage1(
    const float* __restrict__ op1, const float* __restrict__ op2,
    const int* __restrict__ opr,
    const float* __restrict__ enc_op_w1, const float* __restrict__ enc_op_b1,
    int* __restrict__ cnt, int* __restrict__ bucket,
    float* __restrict__ fws, int B)
{
    const int t = threadIdx.x;
    const int blk = blockIdx.x;

    __shared__ float S1s[16 * 68];
    __shared__ float h[32][132];
    __shared__ float t1s[16];
    __shared__ float t1ops[48];
    __shared__ float u2s[64];
    __shared__ float bvaln[32][17];
    __shared__ float part2[4][32];
    __shared__ float o1s[32], o2s[32];
    __shared__ int ops_[32], idxr[32], idxp[32], idxc[32];
    __shared__ int lcnt[16], lpos[32], base[16];

    if (t < 32) { o1s[t] = op1[blk * 32 + t]; o2s[t] = op2[blk * 32 + t]; ops_[t] = opr[blk * 32 + t]; }
    if (t < 16) { lcnt[t] = 0; t1s[t] = fws[OFF_T1 + t]; }
    if (t >= 16 && t < 64)  t1ops[t - 16] = fws[OFF_T1OP + (t - 16)];
    if (t >= 64 && t < 128) u2s[t - 64]   = fws[OFF_U2 + (t - 64)];
    for (int i = t; i < 1024; i += 256) S1s[(i >> 6) * 68 + (i & 63)] = fws[OFF_S1 + i];
    __syncthreads();

    for (int i = t; i < 4096; i += 256) {
        int e = i >> 7, j = i & 127;
        if (j < 64) {
            h[e][j] = fmaxf(fmaf(o1s[e], enc_op_w1[j], enc_op_b1[j]), 0.f);
        } else {
            int j2 = j - 64;
            h[e][j] = fmaxf(fmaf(o2s[e], enc_op_w1[j2], enc_op_w1[64 + j2] + enc_op_b1[j2]), 0.f);
        }
    }
    __syncthreads();

    #pragma unroll
    for (int pp = 0; pp < 2; ++pp) {
        int p = t + pp * 256;
        int e = p >> 4, n = p & 15;
        float a0 = 0.f, a1 = 0.f;
        #pragma unroll 4
        for (int j4 = 0; j4 < 16; ++j4) {
            float4 s  = *(const float4*)&S1s[n * 68 + j4 * 4];
            float4 h0 = *(const float4*)&h[e][j4 * 4];
            float4 h1 = *(const float4*)&h[e][64 + j4 * 4];
            a0 = fmaf(h0.x, s.x, a0); a0 = fmaf(h0.y, s.y, a0);
            a0 = fmaf(h0.z, s.z, a0); a0 = fmaf(h0.w, s.w, a0);
            a1 = fmaf(h1.x, s.x, a1); a1 = fmaf(h1.y, s.y, a1);
            a1 = fmaf(h1.z, s.z, a1); a1 = fmaf(h1.w, s.w, a1);
        }
        bvaln[e][n] = fmaxf(t1s[n] + fmaxf(a0, a1), t1ops[ops_[e] * 16 + n]);
    }
    __syncthreads();

    if (t < 32) {
        float best = -INFINITY; int bn = 0;
        for (int n = 0; n < 16; ++n) {
            float v = bvaln[t][n];
            if (v > best) { best = v; bn = n; }
        }
        idxr[t] = bn;
    }
    __syncthreads();

    if (t < 128) {
        const int e = t & 31, nk = t >> 5, k = nk & 1;
        const int r = idxr[e];
        const float* v2p = &fws[OFF_V2 + nk * 1024 + r];
        float a = 0.f;
        #pragma unroll 4
        for (int j = 0; j < 64; ++j)
            a = fmaf(h[e][k * 64 + j], v2p[j * 16], a);
        part2[nk][e] = a + u2s[nk * 16 + r];
    }
    __syncthreads();
    if (t < 32) {
        idxp[t] = (part2[1][t] > part2[0][t]) ? 1 : 0;
        idxc[t] = (part2[3][t] > part2[2][t]) ? 1 : 0;
    }
    __syncthreads();

    for (int i = t; i < 1024; i += 256) {
        int e = i >> 5, v4 = i & 31;
        int sel = (v4 < 16) ? idxp[e] : idxc[e];
        float4 val = *(const float4*)&h[e][sel * 64 + (v4 & 15) * 4];
        *(float4*)&fws[OFF_VARH + (size_t)(blk * 32 + e) * 128 + v4 * 4] = val;
    }

    if (t < 32) lpos[t] = atomicAdd(&lcnt[idxr[t]], 1);
    __syncthreads();
    if (t < 16 && lcnt[t] > 0) base[t] = atomicAdd(&cnt[t * 32], lcnt[t]);
    __syncthreads();
    if (t < 32) {
        int r = idxr[t];
        bucket[r * B + base[r] + lpos[t]] = blk * 32 + t;
    }
}

// ---------------------------------------------------------------------------
// 64 elems per block. GEMM1 (K=128, N=128, relu) -> GEMM2b (K=128, N=64,
// relu, into A) -> wave-butterfly 64-dot with dec_w2.
__global__ __launch_bounds__(256) void stage2(
    const float* __restrict__ dec_w2, const float* __restrict__ dec_b2,
    const int* __restrict__ cnt, const int* __restrict__ bucket,
    const float* __restrict__ fws, float* __restrict__ out, int B)
{
    const int rule  = blockIdx.y;
    const int start = blockIdx.x * 64;
    const int count = cnt[rule * 32];
    if (start >= count) return;
    const int nelem = min(64, count - start);
    const int t = threadIdx.x;

    __shared__ float A[64][132];   // var_h rows; later relu(out2) in cols 0..63
    __shared__ float H[64][132];
    __shared__ int gi[64];

    if (t < 64) gi[t] = bucket[rule * B + start + ((t < nelem) ? t : 0)];
    __syncthreads();
    for (int i = t; i < 64 * 32; i += 256) {
        int e = i >> 5, v = i & 31;
        *(float4*)&A[e][v * 4] = *(const float4*)&fws[OFF_VARH + (size_t)gi[e] * 128 + v * 4];
    }
    __syncthreads();

    // ---- GEMM1: H = relu(A(64x128) @ W1h[rule](128x128) + b1h)
    {
        const int colg = t & 15, rowg = t >> 4;   // 4 rows each
        const float* W1  = &fws[OFF_W1H + rule * 16384 + colg * 8];
        const float* b1p = &fws[OFF_B1H + rule * 128 + colg * 8];
        float acc[4][8];
        #pragma unroll
        for (int i = 0; i < 4; ++i)
            #pragma unroll
            for (int j = 0; j < 8; ++j) acc[i][j] = b1p[j];
        #pragma unroll 2
        for (int k = 0; k < 128; ++k) {
            const float4 wa = *(const float4*)&W1[k * 128];
            const float4 wb = *(const float4*)&W1[k * 128 + 4];
            float a0 = A[rowg * 4][k], a1 = A[rowg * 4 + 1][k];
            float a2 = A[rowg * 4 + 2][k], a3 = A[rowg * 4 + 3][k];
            acc[0][0] = fmaf(a0, wa.x, acc[0][0]); acc[1][0] = fmaf(a1, wa.x, acc[1][0]);
            acc[2][0] = fmaf(a2, wa.x, acc[2][0]); acc[3][0] = fmaf(a3, wa.x, acc[3][0]);
            acc[0][1] = fmaf(a0, wa.y, acc[0][1]); acc[1][1] = fmaf(a1, wa.y, acc[1][1]);
            acc[2][1] = fmaf(a2, wa.y, acc[2][1]); acc[3][1] = fmaf(a3, wa.y, acc[3][1]);
            acc[0][2] = fmaf(a0, wa.z, acc[0][2]); acc[1][2] = fmaf(a1, wa.z, acc[1][2]);
            acc[2][2] = fmaf(a2, wa.z, acc[2][2]); acc[3][2] = fmaf(a3, wa.z, acc[3][2]);
            acc[0][3] = fmaf(a0, wa.w, acc[0][3]); acc[1][3] = fmaf(a1, wa.w, acc[1][3]);
            acc[2][3] = fmaf(a2, wa.w, acc[2][3]); acc[3][3] = fmaf(a3, wa.w, acc[3][3]);
            acc[0][4] = fmaf(a0, wb.x, acc[0][4]); acc[1][4] = fmaf(a1, wb.x, acc[1][4]);
            acc[2][4] = fmaf(a2, wb.x, acc[2][4]); acc[3][4] = fmaf(a3, wb.x, acc[3][4]);
            acc[0][5] = fmaf(a0, wb.y, acc[0][5]); acc[1][5] = fmaf(a1, wb.y, acc[1][5]);
            acc[2][5] = fmaf(a2, wb.y, acc[2][5]); acc[3][5] = fmaf(a3, wb.y, acc[3][5]);
            acc[0][6] = fmaf(a0, wb.z, acc[0][6]); acc[1][6] = fmaf(a1, wb.z, acc[1][6]);
            acc[2][6] = fmaf(a2, wb.z, acc[2][6]); acc[3][6] = fmaf(a3, wb.z, acc[3][6]);
            acc[0][7] = fmaf(a0, wb.w, acc[0][7]); acc[1][7] = fmaf(a1, wb.w, acc[1][7]);
            acc[2][7] = fmaf(a2, wb.w, acc[2][7]); acc[3][7] = fmaf(a3, wb.w, acc[3][7]);
        }
        #pragma unroll
        for (int i = 0; i < 4; ++i)
            #pragma unroll
            for (int j = 0; j < 8; ++j)
                H[rowg * 4 + i][colg * 8 + j] = fmaxf(acc[i][j], 0.f);
    }
    __syncthreads();   // H ready; all A reads done

    // ---- GEMM2b: A[e][0..63] = relu(H(64x128) @ W2d[rule](128x64) + b2d)
    {
        const int colg = t & 7, rowg = t >> 3;    // 2 rows each
        const float* W2  = &fws[OFF_W2D + rule * 8192 + colg * 8];
        const float* b2p = &fws[OFF_B2D + rule * 64 + colg * 8];
        float acc[2][8];
        #pragma unroll
        for (int j = 0; j < 8; ++j) { acc[0][j] = b2p[j]; acc[1][j] = b2p[j]; }
        #pragma unroll 4
        for (int k = 0; k < 128; ++k) {
            const float4 wa = *(const float4*)&W2[k * 64];
            const float4 wb = *(const float4*)&W2[k * 64 + 4];
            float h0 = H[rowg * 2][k], h1 = H[rowg * 2 + 1][k];
            acc[0][0] = fmaf(h0, wa.x, acc[0][0]); acc[1][0] = fmaf(h1, wa.x, acc[1][0]);
            acc[0][1] = fmaf(h0, wa.y, acc[0][1]); acc[1][1] = fmaf(h1, wa.y, acc[1][1]);
            acc[0][2] = fmaf(h0, wa.z, acc[0][2]); acc[1][2] = fmaf(h1, wa.z, acc[1][2]);
            acc[0][3] = fmaf(h0, wa.w, acc[0][3]); acc[1][3] = fmaf(h1, wa.w, acc[1][3]);
            acc[0][4] = fmaf(h0, wb.x, acc[0][4]); acc[1][4] = fmaf(h1, wb.x, acc[1][4]);
            acc[0][5] = fmaf(h0, wb.y, acc[0][5]); acc[1][5] = fmaf(h1, wb.y, acc[1][5]);
            acc[0][6] = fmaf(h0, wb.z, acc[0][6]); acc[1][6] = fmaf(h1, wb.z, acc[1][6]);
            acc[0][7] = fmaf(h0, wb.w, acc[0][7]); acc[1][7] = fmaf(h1, wb.w, acc[1][7]);
        }
        // A reads all completed before the previous barrier; safe to overwrite.
        #pragma unroll
        for (int i = 0; i < 2; ++i)
            #pragma unroll
            for (int j = 0; j < 8; ++j)
                A[rowg * 2 + i][colg * 8 + j] = fmaxf(acc[i][j], 0.f);
    }
    __syncthreads();

    // ---- final: out = relu_out2 . dec_w2 + dec_b2 (wave butterfly)
    {
        const int wv = t >> 6, lane = t & 63;
        const float w2v = dec_w2[lane];
        const float b2v = dec_b2[0];
        for (int i = 0; i < 16; ++i) {
            int e = wv * 16 + i;
            if (e >= nelem) break;
            float v = A[e][lane] * w2v;
            #pragma unroll
            for (int off = 32; off; off >>= 1) v += __shfl_down(v, off);
            if (lane == 0) out[gi[e]] = v + b2v;
        }
    }
}

// ---------------------------------------------------------------------------
extern "C" void kernel_launch(void* const* d_in, const int* in_sizes, int n_in,
                              void* d_out, int out_size, void* d_ws, size_t ws_size,
                              hipStream_t stream)
{
    const float* op1        = (const float*)d_in[0];
    const float* op2        = (const float*)d_in[1];
    const int*   opr        = (const int*)  d_in[2];
    const float* enc_op_w1  = (const float*)d_in[3];
    const float* enc_op_b1  = (const float*)d_in[4];
    const float* enc_op_w2  = (const float*)d_in[5];
    const float* enc_op_b2  = (const float*)d_in[6];
    const float* enc_opr_w1 = (const float*)d_in[7];
    const float* enc_opr_b1 = (const float*)d_in[8];
    const float* enc_opr_w2 = (const float*)d_in[9];
    const float* enc_opr_b2 = (const float*)d_in[10];
    const float* dec_w1     = (const float*)d_in[11];
    const float* dec_b1     = (const float*)d_in[12];
    const float* dec_w2     = (const float*)d_in[13];
    const float* dec_b2     = (const float*)d_in[14];
    const float* rules_emb  = (const float*)d_in[15];
    const float* rule_W1    = (const float*)d_in[16];
    const float* rule_b1    = (const float*)d_in[17];
    const float* rule_W2    = (const float*)d_in[18];
    const float* rule_b2    = (const float*)d_in[19];
    const float* s1_q_w     = (const float*)d_in[20];
    const float* s1_q_b     = (const float*)d_in[21];
    const float* s1_k_w     = (const float*)d_in[22];
    const float* s1_k_b     = (const float*)d_in[23];
    const float* s2_q_w     = (const float*)d_in[24];
    const float* s2_q_b     = (const float*)d_in[25];
    const float* s2_k_w     = (const float*)d_in[26];
    const float* s2_k_b     = (const float*)d_in[27];

    float* out = (float*)d_out;
    const int B = in_sizes[0];

    int*   cnt    = (int*)d_ws;                 // 16*32 padded counters
    int*   bucket = cnt + 16 * 32;              // 16*B
    float* fws    = (float*)(bucket + 16 * B);  // float region (16B aligned)

    setup_fused<<<49, 256, 0, stream>>>(
        rules_emb, s1_k_w, s1_k_b, s2_k_w, s2_k_b,
        enc_opr_w1, enc_opr_b1, enc_opr_w2, enc_opr_b2,
        enc_op_w2, enc_op_b2, s1_q_w, s1_q_b, s2_q_w, s2_q_b,
        rule_W1, rule_b1, rule_W2, rule_b2, dec_w1, dec_b1, cnt, fws);

    stage1<<<B / 32, 256, 0, stream>>>(
        op1, op2, opr, enc_op_w1, enc_op_b1, cnt, bucket, fws, B);

    stage2<<<dim3(B / 64, 16), 256, 0, stream>>>(
        dec_w2, dec_b2, cnt, bucket, fws, out, B);
}